// Round 1
// baseline (839.249 us; speedup 1.0000x reference)
//
#include <hip/hip_runtime.h>
#include <math.h>

#define NS 4096      // samples
#define NC 512       // clusters
#define ND 64        // feature dim
#define NK 10        // classes
#define GROUPS 64    // cluster groups for gamma kernel
#define CPG (NC/GROUPS)   // 8 clusters per group
#define TILES (NS/64)     // 64 sample tiles (64 threads/block, 1 sample/thread)

// ws layout (floats):
//  Binv [NC][ND*ND]        @ 0
//  bvec [NC][ND]           @ NC*ND*ND            (b = -2 * Sinv mu)
//  kcon [NC]                                      (mu^T Sinv mu)
//  labf [NC]                                      (class index per cluster, as float)
//  part [GROUPS][NS][16]                          (partial numer[10], denom, gmax, gidx)

__global__ __launch_bounds__(256) void prep_kernel(
    const float* __restrict__ S, const float* __restrict__ n,
    const float* __restrict__ mu, const int* __restrict__ clab,
    float* __restrict__ Binv, float* __restrict__ bvec,
    float* __restrict__ kcon, float* __restrict__ labf)
{
    const int c = blockIdx.x;
    const int t = threadIdx.x;
    __shared__ float A[ND][ND + 1];
    __shared__ float V[ND][ND + 1];
    __shared__ float muS[ND], yS[ND];

    const float inv_nc = 1.0f / n[c];
    for (int idx = t; idx < ND * ND; idx += 256) {
        const int i = idx >> 6, j = idx & 63;
        float v = S[(size_t)c * ND * ND + idx] * inv_nc;   // Sigma = S/n
        if (i == j) v += 1e-6f;                            // + eps*I
        A[i][j] = v;
        V[i][j] = (i == j) ? 1.0f : 0.0f;
    }
    __syncthreads();

    // Gauss-Jordan (SPD: no pivoting). Each thread owns row i=t>>2, 16 cols from j0.
    const int i = t >> 2;
    const int j0 = (t & 3) << 4;
    for (int k = 0; k < ND; ++k) {
        const float ipiv = 1.0f / A[k][k];
        __syncthreads();
        if (t < ND)            A[k][t]      *= ipiv;
        else if (t < 2 * ND)   V[k][t - ND] *= ipiv;
        __syncthreads();
        const float f = A[i][k];
        __syncthreads();
        if (i != k) {
            #pragma unroll
            for (int jj = 0; jj < 16; ++jj) {
                A[i][j0 + jj] -= f * A[k][j0 + jj];
                V[i][j0 + jj] -= f * V[k][j0 + jj];
            }
        }
        __syncthreads();
    }

    if (t < ND) muS[t] = mu[c * ND + t];
    __syncthreads();
    if (t < ND) {
        float acc = 0.f;
        for (int j = 0; j < ND; ++j) acc += V[t][j] * muS[j];
        yS[t] = acc;
        bvec[c * ND + t] = -2.0f * acc;
    }
    __syncthreads();
    if (t == 0) {
        float kk = 0.f;
        for (int q = 0; q < ND; ++q) kk += muS[q] * yS[q];
        kcon[c] = kk;
        int lab = 0;
        for (int q = 0; q < NK; ++q) if (clab[c * NK + q] != 0) lab = q;
        labf[c] = (float)lab;
    }
    __syncthreads();
    for (int idx = t; idx < ND * ND; idx += 256)
        Binv[(size_t)c * ND * ND + idx] = V[idx >> 6][idx & 63];
}

// One thread = one sample (z in registers). B rows have wave-uniform addresses
// -> should compile to s_load + v_fmac(v,s,v): VALU-bound fp32.
__global__ __launch_bounds__(64) void gamma_kernel(
    const float* __restrict__ data, const float* __restrict__ Binv,
    const float* __restrict__ bvec, const float* __restrict__ kcon,
    const float* __restrict__ labf, float* __restrict__ part)
{
    const int tile = blockIdx.x & (TILES - 1);
    const int grp  = blockIdx.x / TILES;
    const int s = tile * 64 + threadIdx.x;

    float z[ND];
    const float4* zp = (const float4*)(data + (size_t)s * ND);
    #pragma unroll
    for (int q = 0; q < ND / 4; ++q) {
        const float4 v = zp[q];
        z[4 * q] = v.x; z[4 * q + 1] = v.y; z[4 * q + 2] = v.z; z[4 * q + 3] = v.w;
    }

    float numer[NK];
    #pragma unroll
    for (int q = 0; q < NK; ++q) numer[q] = 0.f;
    float denom = 0.f, gmax = -1.f;
    int gidx = 0;

    const int c0 = grp * CPG;
    for (int cc = 0; cc < CPG; ++cc) {
        const int c = c0 + cc;
        const float* __restrict__ B  = Binv + (size_t)c * ND * ND;
        const float* __restrict__ bv = bvec + c * ND;

        float b0 = 0.f, b1 = 0.f, b2 = 0.f, b3 = 0.f;
        #pragma unroll
        for (int j = 0; j < ND; j += 4) {
            b0 += bv[j]     * z[j];
            b1 += bv[j + 1] * z[j + 1];
            b2 += bv[j + 2] * z[j + 2];
            b3 += bv[j + 3] * z[j + 3];
        }
        float d2 = kcon[c] + ((b0 + b1) + (b2 + b3));

        for (int i = 0; i < ND; ++i) {
            const float* __restrict__ row = B + i * ND;
            float y0 = 0.f, y1 = 0.f, y2 = 0.f, y3 = 0.f;
            #pragma unroll
            for (int j = 0; j < ND; j += 4) {
                y0 += row[j]     * z[j];
                y1 += row[j + 1] * z[j + 1];
                y2 += row[j + 2] * z[j + 2];
                y3 += row[j + 3] * z[j + 3];
            }
            d2 += ((y0 + y1) + (y2 + y3)) * z[i];
        }

        const float G = __expf(-0.5f * d2);   // fp32 underflow -> 0, matching ref
        denom += G;
        const int lab = (int)labf[c];
        #pragma unroll
        for (int q = 0; q < NK; ++q) numer[q] += (q == lab) ? G : 0.f;
        if (G > gmax) { gmax = G; gidx = c; }   // strict > keeps first index
    }

    float* __restrict__ p = part + ((size_t)grp * NS + s) * 16;
    #pragma unroll
    for (int q = 0; q < NK; ++q) p[q] = numer[q];
    p[10] = denom; p[11] = gmax; p[12] = (float)gidx;
}

__global__ __launch_bounds__(64) void reduce_kernel(
    const float* __restrict__ part, float* __restrict__ out)
{
    const int s = blockIdx.x * 64 + threadIdx.x;
    float numer[NK];
    #pragma unroll
    for (int q = 0; q < NK; ++q) numer[q] = 0.f;
    float denom = 0.f, gmax = -1.f, gidx = 0.f;

    for (int g = 0; g < GROUPS; ++g) {       // ascending group = ascending cluster idx
        const float* __restrict__ p = part + ((size_t)g * NS + s) * 16;
        #pragma unroll
        for (int q = 0; q < NK; ++q) numer[q] += p[q];
        denom += p[10];
        const float gm = p[11];
        if (gm > gmax) { gmax = gm; gidx = p[12]; }
    }

    const float inv = 1.0f / (denom + 1e-12f);
    float best = -1.f; int pk = 0;
    #pragma unroll
    for (int q = 0; q < NK; ++q) {
        const float sc = numer[q] * inv;
        out[(size_t)s * NK + q] = sc;
        if (sc > best) { best = sc; pk = q; }
    }
    out[(size_t)NS * NK + s]      = (float)pk;   // pred
    out[(size_t)NS * NK + NS + s] = gidx;        // clusters
}

extern "C" void kernel_launch(void* const* d_in, const int* in_sizes, int n_in,
                              void* d_out, int out_size, void* d_ws, size_t ws_size,
                              hipStream_t stream)
{
    const float* data = (const float*)d_in[0];
    // d_in[1] = labels: unused in inference path
    const float* n    = (const float*)d_in[2];
    const float* mu   = (const float*)d_in[3];
    const float* S    = (const float*)d_in[4];
    const int*   clab = (const int*)d_in[5];

    float* ws   = (float*)d_ws;
    float* Binv = ws;
    float* bvec = Binv + (size_t)NC * ND * ND;
    float* kcon = bvec + (size_t)NC * ND;
    float* labf = kcon + NC;
    float* part = labf + NC;
    float* out  = (float*)d_out;

    hipLaunchKernelGGL(prep_kernel,  dim3(NC),            dim3(256), 0, stream,
                       S, n, mu, clab, Binv, bvec, kcon, labf);
    hipLaunchKernelGGL(gamma_kernel, dim3(TILES * GROUPS), dim3(64), 0, stream,
                       data, Binv, bvec, kcon, labf, part);
    hipLaunchKernelGGL(reduce_kernel, dim3(NS / 64),       dim3(64), 0, stream,
                       part, out);
}

// Round 2
// 269.829 us; speedup vs baseline: 3.1103x; 3.1103x over previous
//
#include <hip/hip_runtime.h>
#include <hip/hip_bf16.h>
#include <math.h>

#define NS 4096      // samples
#define NC 512       // clusters
#define ND 64        // feature dim
#define NK 10        // classes
#define NPAIR 2080   // upper-triangle pairs (e<=d) of 64x64
#define KP 2176      // 2080 + 64 (linear) + 1 (const) + 31 zero-pad; 68*32
#define BOFF 2080
#define KOFF 2144
#define KT_STEPS (KP / 32)   // 68

typedef __attribute__((ext_vector_type(8))) short short8;
typedef __attribute__((ext_vector_type(8))) unsigned short ushort8;
typedef __attribute__((ext_vector_type(4))) float floatx4;

__device__ inline unsigned short f2b(float x) {
    __hip_bfloat16 h = __float2bfloat16(x);           // RNE
    return __builtin_bit_cast(unsigned short, h);
}
__device__ inline float b2f(unsigned short u) {
    __hip_bfloat16 h = __builtin_bit_cast(__hip_bfloat16, u);
    return __bfloat162float(h);
}

// ---------------- pair-index tables ----------------
__global__ void table_kernel(int* __restrict__ eop, int* __restrict__ dop) {
    const int e = threadIdx.x;                        // 64 threads
    int off = e * 64 - (e * (e - 1)) / 2;             // row e starts here
    for (int d = e; d < 64; ++d) { eop[off + d - e] = e; dop[off + d - e] = d; }
}

// ---------------- Sigma^-1 via Gauss-Jordan (unchanged, known-correct) ----------------
__global__ __launch_bounds__(256) void prep_kernel(
    const float* __restrict__ S, const float* __restrict__ n,
    const float* __restrict__ mu, const int* __restrict__ clab,
    float* __restrict__ Binv, float* __restrict__ bvec,
    float* __restrict__ kcon, float* __restrict__ labf)
{
    const int c = blockIdx.x;
    const int t = threadIdx.x;
    __shared__ float A[ND][ND + 1];
    __shared__ float V[ND][ND + 1];
    __shared__ float muS[ND], yS[ND];

    const float inv_nc = 1.0f / n[c];
    for (int idx = t; idx < ND * ND; idx += 256) {
        const int i = idx >> 6, j = idx & 63;
        float v = S[(size_t)c * ND * ND + idx] * inv_nc;   // Sigma = S/n
        if (i == j) v += 1e-6f;                            // + eps*I
        A[i][j] = v;
        V[i][j] = (i == j) ? 1.0f : 0.0f;
    }
    __syncthreads();

    const int i = t >> 2;
    const int j0 = (t & 3) << 4;
    for (int k = 0; k < ND; ++k) {
        const float ipiv = 1.0f / A[k][k];
        __syncthreads();
        if (t < ND)            A[k][t]      *= ipiv;
        else if (t < 2 * ND)   V[k][t - ND] *= ipiv;
        __syncthreads();
        const float f = A[i][k];
        __syncthreads();
        if (i != k) {
            #pragma unroll
            for (int jj = 0; jj < 16; ++jj) {
                A[i][j0 + jj] -= f * A[k][j0 + jj];
                V[i][j0 + jj] -= f * V[k][j0 + jj];
            }
        }
        __syncthreads();
    }

    if (t < ND) muS[t] = mu[c * ND + t];
    __syncthreads();
    if (t < ND) {
        float acc = 0.f;
        for (int j = 0; j < ND; ++j) acc += V[t][j] * muS[j];
        yS[t] = acc;
        bvec[c * ND + t] = -2.0f * acc;
    }
    __syncthreads();
    if (t == 0) {
        float kk = 0.f;
        for (int q = 0; q < ND; ++q) kk += muS[q] * yS[q];
        kcon[c] = kk;
        int lab = 0;
        for (int q = 0; q < NK; ++q) if (clab[c * NK + q] != 0) lab = q;
        labf[c] = (float)lab;
    }
    __syncthreads();
    for (int idx = t; idx < ND * ND; idx += 256)
        Binv[(size_t)c * ND * ND + idx] = V[idx >> 6][idx & 63];
}

// ---------------- pack beta_c = [sym-folded Binv, b, k, 0pad] as bf16 hi/lo ----------------
__global__ __launch_bounds__(256) void pack_kernel(
    const float* __restrict__ Binv, const float* __restrict__ bvec,
    const float* __restrict__ kcon, const int* __restrict__ eop,
    const int* __restrict__ dop, unsigned short* __restrict__ Bph,
    unsigned short* __restrict__ Bpl)
{
    const int c = blockIdx.x;
    const float* __restrict__ B = Binv + (size_t)c * ND * ND;
    for (int p = threadIdx.x; p < KP; p += 256) {
        float val;
        if (p < NPAIR) {
            const int e = eop[p], d = dop[p];
            val = (e == d) ? B[e * 64 + e] : (B[e * 64 + d] + B[d * 64 + e]);
        } else if (p < KOFF) val = bvec[c * ND + (p - BOFF)];
        else if (p == KOFF)  val = kcon[c];
        else                 val = 0.f;
        const unsigned short h = f2b(val);
        const unsigned short l = f2b(val - b2f(h));
        Bph[(size_t)c * KP + p] = h;
        Bpl[(size_t)c * KP + p] = l;
    }
}

// ---------------- Q rows: [z_e*z_d (e<=d), z, 1, 0pad] as bf16 hi/lo ----------------
__global__ __launch_bounds__(256) void qbuild_kernel(
    const float* __restrict__ data, const int* __restrict__ eop,
    const int* __restrict__ dop, unsigned short* __restrict__ Qh,
    unsigned short* __restrict__ Ql)
{
    const int s = blockIdx.x;
    __shared__ float z[ND];
    if (threadIdx.x < ND) z[threadIdx.x] = data[(size_t)s * ND + threadIdx.x];
    __syncthreads();
    for (int p = threadIdx.x; p < KP; p += 256) {
        float val;
        if (p < NPAIR)      val = z[eop[p]] * z[dop[p]];
        else if (p < KOFF)  val = z[p - BOFF];
        else if (p == KOFF) val = 1.0f;
        else                val = 0.f;
        const unsigned short h = f2b(val);
        const unsigned short l = f2b(val - b2f(h));
        Qh[(size_t)s * KP + p] = h;
        Ql[(size_t)s * KP + p] = l;
    }
}

// ---------------- d2[s][c] = Q · Beta^T via bf16x3 MFMA ----------------
// Block tile: 32 samples x 256 clusters, K-chunk 32, 4 waves (each 32x64).
__global__ __launch_bounds__(256) void gemm_kernel(
    const unsigned short* __restrict__ Qh, const unsigned short* __restrict__ Ql,
    const unsigned short* __restrict__ Bph, const unsigned short* __restrict__ Bpl,
    float* __restrict__ d2)
{
    __shared__ unsigned short AhS[32][40], AlS[32][40];    // +8 pad vs 32
    __shared__ unsigned short BhS[256][40], BlS[256][40];

    const int tid  = threadIdx.x;
    const int lane = tid & 63, w = tid >> 6;
    const int quad = lane >> 4, rlo = lane & 15;
    const int m0 = blockIdx.x * 32;      // sample tile (fast-varying blockIdx -> shared beta tile stays L2-hot)
    const int n0 = blockIdx.y * 256;     // cluster tile

    // staging assignments: A (Qh+Ql): 256 16B-segs; B: 2048 segs (8 iters)
    const int aplane = tid >> 7, aidx = tid & 127;
    const int arow = aidx >> 2, aseg = aidx & 3;
    const unsigned short* aSrc = (aplane ? Ql : Qh) + (size_t)(m0 + arow) * KP + aseg * 8;
    unsigned short* aDst = (aplane ? &AlS[0][0] : &AhS[0][0]) + arow * 40 + aseg * 8;

    const unsigned short* bSrc[8];
    unsigned short* bDst[8];
    #pragma unroll
    for (int it = 0; it < 8; ++it) {
        const int idx2 = it * 256 + tid;
        const int bplane = idx2 >> 10, idx = idx2 & 1023;
        const int br = idx >> 2, bseg = idx & 3;
        bSrc[it] = (bplane ? Bpl : Bph) + (size_t)(n0 + br) * KP + bseg * 8;
        bDst[it] = (bplane ? &BlS[0][0] : &BhS[0][0]) + br * 40 + bseg * 8;
    }

    ushort8 pa, pb[8];
    // prefetch kt=0
    pa = *(const ushort8*)(aSrc);
    #pragma unroll
    for (int it = 0; it < 8; ++it) pb[it] = *(const ushort8*)(bSrc[it]);

    floatx4 acc[2][4] = {};

    for (int kt = 0; kt < KT_STEPS; ++kt) {
        __syncthreads();
        *(ushort8*)aDst = pa;
        #pragma unroll
        for (int it = 0; it < 8; ++it) *(ushort8*)bDst[it] = pb[it];
        __syncthreads();

        if (kt + 1 < KT_STEPS) {
            const int ko = (kt + 1) * 32;
            pa = *(const ushort8*)(aSrc + ko);
            #pragma unroll
            for (int it = 0; it < 8; ++it) pb[it] = *(const ushort8*)(bSrc[it] + ko);
        }

        short8 ah[2], al[2], bh[4], bl[4];
        #pragma unroll
        for (int i = 0; i < 2; ++i) {
            ah[i] = *(const short8*)&AhS[i * 16 + rlo][quad * 8];
            al[i] = *(const short8*)&AlS[i * 16 + rlo][quad * 8];
        }
        #pragma unroll
        for (int j = 0; j < 4; ++j) {
            const int r = w * 64 + j * 16 + rlo;
            bh[j] = *(const short8*)&BhS[r][quad * 8];
            bl[j] = *(const short8*)&BlS[r][quad * 8];
        }
        #pragma unroll
        for (int i = 0; i < 2; ++i)
            #pragma unroll
            for (int j = 0; j < 4; ++j) {
                acc[i][j] = __builtin_amdgcn_mfma_f32_16x16x32_bf16(al[i], bh[j], acc[i][j], 0, 0, 0);
                acc[i][j] = __builtin_amdgcn_mfma_f32_16x16x32_bf16(ah[i], bl[j], acc[i][j], 0, 0, 0);
                acc[i][j] = __builtin_amdgcn_mfma_f32_16x16x32_bf16(ah[i], bh[j], acc[i][j], 0, 0, 0);
            }
    }

    // C layout (verified m89): col = lane&15, row = (lane>>4)*4 + reg
    #pragma unroll
    for (int i = 0; i < 2; ++i)
        #pragma unroll
        for (int j = 0; j < 4; ++j) {
            const int m = m0 + i * 16 + quad * 4;
            const int n = n0 + w * 64 + j * 16 + rlo;
            #pragma unroll
            for (int r = 0; r < 4; ++r)
                d2[(size_t)(m + r) * NC + n] = acc[i][j][r];
        }
}

// ---------------- scores / argmaxes: one wave per sample ----------------
__global__ __launch_bounds__(64) void score_kernel(
    const float* __restrict__ d2, const float* __restrict__ labf,
    float* __restrict__ out)
{
    const int s = blockIdx.x;
    const int l = threadIdx.x;

    float numer[NK];
    #pragma unroll
    for (int q = 0; q < NK; ++q) numer[q] = 0.f;
    float denom = 0.f, gmax = -1.f;
    int gidx = 0;

    for (int i = 0; i < NC / 64; ++i) {          // lane-strided, ascending per lane
        const int c = l + i * 64;
        const float G = __expf(-0.5f * d2[(size_t)s * NC + c]);
        denom += G;
        const int lab = (int)labf[c];
        #pragma unroll
        for (int q = 0; q < NK; ++q) numer[q] += (q == lab) ? G : 0.f;
        if (G > gmax) { gmax = G; gidx = c; }
    }

    // wave reduction (width 64); ties -> lowest cluster index (jnp first-max)
    #pragma unroll
    for (int off = 32; off > 0; off >>= 1) {
        const float og = __shfl_down(gmax, off);
        const int   oi = __shfl_down(gidx, off);
        if (og > gmax || (og == gmax && oi < gidx)) { gmax = og; gidx = oi; }
        denom += __shfl_down(denom, off);
        #pragma unroll
        for (int q = 0; q < NK; ++q) numer[q] += __shfl_down(numer[q], off);
    }

    if (l == 0) {
        const float inv = 1.0f / (denom + 1e-12f);
        float best = -1.f; int pk = 0;
        #pragma unroll
        for (int q = 0; q < NK; ++q) {
            const float sc = numer[q] * inv;
            out[(size_t)s * NK + q] = sc;
            if (sc > best) { best = sc; pk = q; }
        }
        out[(size_t)NS * NK + s]      = (float)pk;    // pred
        out[(size_t)NS * NK + NS + s] = (float)gidx;  // clusters
    }
}

extern "C" void kernel_launch(void* const* d_in, const int* in_sizes, int n_in,
                              void* d_out, int out_size, void* d_ws, size_t ws_size,
                              hipStream_t stream)
{
    const float* data = (const float*)d_in[0];
    const float* n    = (const float*)d_in[2];
    const float* mu   = (const float*)d_in[3];
    const float* S    = (const float*)d_in[4];
    const int*   clab = (const int*)d_in[5];

    // ws byte layout (Binv/bvec/kcon alias the Qh region: dead before qbuild runs)
    char* w = (char*)d_ws;
    unsigned short* Qh  = (unsigned short*)(w);                 // 17,825,792 B
    unsigned short* Ql  = (unsigned short*)(w + 17825792);      // 17,825,792 B
    unsigned short* Bph = (unsigned short*)(w + 35651584);      //  2,228,224 B
    unsigned short* Bpl = (unsigned short*)(w + 37879808);      //  2,228,224 B
    float* d2   = (float*)(w + 40108032);                       //  8,388,608 B
    float* labf = (float*)(w + 48496640);                       //      2,048 B
    int*   eop  = (int*)  (w + 48498688);                       //      8,320 B
    int*   dop  = (int*)  (w + 48507008);                       //      8,320 B  (end 48,515,328)
    float* Binv = (float*)(w);                                  // alias in Qh region
    float* bvec = (float*)(w + 8388608);
    float* kcon = (float*)(w + 8519680);

    hipLaunchKernelGGL(table_kernel, dim3(1),   dim3(64),  0, stream, eop, dop);
    hipLaunchKernelGGL(prep_kernel,  dim3(NC),  dim3(256), 0, stream,
                       S, n, mu, clab, Binv, bvec, kcon, labf);
    hipLaunchKernelGGL(pack_kernel,  dim3(NC),  dim3(256), 0, stream,
                       Binv, bvec, kcon, eop, dop, Bph, Bpl);
    hipLaunchKernelGGL(qbuild_kernel, dim3(NS), dim3(256), 0, stream,
                       data, eop, dop, Qh, Ql);
    hipLaunchKernelGGL(gemm_kernel,  dim3(NS / 32, NC / 256), dim3(256), 0, stream,
                       Qh, Ql, Bph, Bpl, d2);
    hipLaunchKernelGGL(score_kernel, dim3(NS),  dim3(64),  0, stream,
                       d2, labf, (float*)d_out);
}